// Round 3
// baseline (7983.532 us; speedup 1.0000x reference)
//
#include <hip/hip_runtime.h>
#include <cstdint>
#include <cstddef>

#define T_LEN   4096
#define B_SZ    32
#define H_DIM   128
#define DX      128
#define K_CLS   10
#define G       4                  // chains per block (same direction)
#define CHUNK   8
#define NROW    (G * CHUNK)        // 32 rows per chunk-tile
#define NCHUNKS (T_LEN / CHUNK)    // 512
#define XA_LD   136
#define HI_LD   136
#define XH_W    520                // padded: breaks 4-way bank conflict on D-stores

typedef _Float16 half2v  __attribute__((ext_vector_type(2)));
typedef _Float16 half8   __attribute__((ext_vector_type(8)));
typedef float    floatx4 __attribute__((ext_vector_type(4)));

__device__ __forceinline__ float dot2f(unsigned int w, unsigned int h, float acc) {
  return __builtin_amdgcn_fdot2(__builtin_bit_cast(half2v, w),
                                __builtin_bit_cast(half2v, h), acc, false);
}

__device__ __forceinline__ unsigned int packh2(float a, float b) {
  half2v h;
  h.x = (_Float16)a;
  h.y = (_Float16)b;
  return __builtin_bit_cast(unsigned int, h);
}

// x + x(lane^1) via DPP quad_perm(1,0,3,2); both lanes of the pair get the sum.
__device__ __forceinline__ float dpp_xor1_add(float x) {
  int xi = __builtin_bit_cast(int, x);
  int yi = __builtin_amdgcn_update_dpp(xi, xi, 0xB1, 0xF, 0xF, false);
  return x + __builtin_bit_cast(float, yi);
}

__device__ __forceinline__ float sigm(float x) {
  x = fminf(fmaxf(x, -30.f), 30.f);
  return __builtin_amdgcn_rcpf(1.f + __expf(-x));
}

__device__ __forceinline__ float tanhfast(float x) {
  x = fminf(fmaxf(x, -15.f), 15.f);
  float t = __expf(-2.f * x);
  return (1.f - t) * __builtin_amdgcn_rcpf(1.f + t);
}

// LDS-only barrier: waits ds ops (lgkmcnt) but does NOT drain vmcnt, so
// in-flight global prefetch loads don't stall every scan-step barrier.
__device__ __forceinline__ void bar_lgkm() {
  asm volatile("s_waitcnt lgkmcnt(0)\n\ts_barrier" ::: "memory");
}

__global__ void __launch_bounds__(256) init_out_kernel(float* __restrict__ out,
                                                       const float* __restrict__ bfc) {
  int i = blockIdx.x * 256 + threadIdx.x;
  if (i < B_SZ * T_LEN * K_CLS) out[i] = bfc[i % K_CLS];
}

__global__ void __launch_bounds__(256) cvt_wih_kernel(const float* __restrict__ a,
                                                      const float* __restrict__ b,
                                                      _Float16* __restrict__ oa,
                                                      _Float16* __restrict__ ob) {
  int i = blockIdx.x * 256 + threadIdx.x;
  if (i < 3 * H_DIM * DX) {
    oa[i] = (_Float16)a[i];
    ob[i] = (_Float16)b[i];
  }
}

__global__ void __launch_bounds__(256, 1)
gru_bidir_kernel(const float* __restrict__ x,
                 const float* __restrict__ Whh_f, const float* __restrict__ bih_f,
                 const float* __restrict__ bhh_f,
                 const float* __restrict__ Whh_b, const float* __restrict__ bih_b,
                 const float* __restrict__ bhh_b,
                 const _Float16* __restrict__ wih16_f, const _Float16* __restrict__ wih16_b,
                 const float* __restrict__ Wfc, float* __restrict__ out) {
  const int tid = threadIdx.x;
  const int bid = blockIdx.x;
  const int dir = bid >> 3;            // 8 fwd blocks, 8 bwd blocks
  const int b0  = (bid & 7) * G;

  const float* Whh = dir ? Whh_b : Whh_f;
  const float* bih = dir ? bih_b : bih_f;
  const float* bhh = dir ? bhh_b : bhh_f;
  const _Float16* Wih16 = dir ? wih16_b : wih16_f;

  const int lane  = tid & 63;
  const int wv    = tid >> 6;          // 0..3
  const int mcol  = lane & 15;         // MFMA n/m index
  const int mquad = lane >> 4;         // MFMA k-group
  const int j     = tid >> 1;          // hidden row 0..127 (scan)
  const int q     = tid & 1;           // k-half (scan)

  __shared__ __align__(16) _Float16 xAf[NROW * XA_LD];     // x tile (rows = c*8+s)
  __shared__ __align__(16) _Float16 xh2f[NROW * XH_W];     // xp tile [row][j*4+gate]
  __shared__ __align__(16) _Float16 histf[NROW * HI_LD];   // h history for FC
  __shared__ __align__(16) _Float16 hbuf[2][G][H_DIM];     // double-buffered h per chain

  // ---- recurrent weights: 32 packed f16 pairs per gate (k-half q) ----
  unsigned int whr[32], whz[32], whn[32];
  {
    const float* Wr = Whh + (size_t)j * H_DIM + q * 64;
    const float* Wz = Whh + (size_t)(H_DIM + j) * H_DIM + q * 64;
    const float* Wn = Whh + (size_t)(2 * H_DIM + j) * H_DIM + q * 64;
#pragma unroll
    for (int i = 0; i < 32; ++i) {
      whr[i] = packh2(Wr[2 * i], Wr[2 * i + 1]);
      whz[i] = packh2(Wz[2 * i], Wz[2 * i + 1]);
      whn[i] = packh2(Wn[2 * i], Wn[2 * i + 1]);
    }
  }
  const float cbr  = bih[j] + bhh[j];
  const float cbz  = bih[H_DIM + j] + bhh[H_DIM + j];
  const float bin_ = bih[2 * H_DIM + j];
  const float bhn  = bhh[2 * H_DIM + j];

  // ---- Wfc fragments (stationary) ----
  half8 fcfrag[4];
#pragma unroll
  for (int ks = 0; ks < 4; ++ks) {
    half8 v;
#pragma unroll
    for (int e = 0; e < 8; ++e) {
      int cc = ks * 32 + mquad * 8 + e;
      v[e] = (mcol < K_CLS) ? (_Float16)Wfc[(size_t)mcol * (2 * H_DIM) + dir * H_DIM + cc]
                            : (_Float16)0.f;
    }
    fcfrag[ks] = v;
  }

  if (tid < 128) {
#pragma unroll
    for (int c = 0; c < G; ++c) hbuf[0][c][tid] = (_Float16)0.f;
  }

  // ---- x prefetch: thread covers tile-row (chain pc, step ps), 16 floats ----
  const int prow  = tid >> 3;          // 0..31
  const int pc    = prow >> 3;         // chain
  const int ps    = prow & 7;          // step-in-chunk
  const int cbase = (tid & 7) * 16;
  float4 px0, px1, px2, px3;
  {
    int t0 = dir ? (T_LEN - 1 - ps) : ps;
    const float* xp = x + ((size_t)(b0 + pc) * T_LEN + t0) * DX + cbase;
    px0 = *(const float4*)xp;       px1 = *(const float4*)(xp + 4);
    px2 = *(const float4*)(xp + 8); px3 = *(const float4*)(xp + 12);
  }

  float hold0 = 0.f, hold1 = 0.f, hold2 = 0.f, hold3 = 0.f;
  int p = 0;
  __syncthreads();

  // ---- helpers ----
  auto ldhh = [&](int c, uint4* h) {
    const uint4* hb = (const uint4*)&hbuf[p][c][q * 64];
#pragma unroll
    for (int i = 0; i < 8; ++i) h[i] = hb[i];
  };
  auto ldxv = [&](int c, int s) -> uint2 {
    return *(const uint2*)&xh2f[(size_t)(c * CHUNK + s) * XH_W + j * 4];
  };
  auto stepc = [&](int c, int s, const uint4* hv, uint2 xv, float hold) -> float {
    unsigned int hh[32];
#pragma unroll
    for (int i = 0; i < 8; ++i) {
      hh[4 * i]     = hv[i].x;
      hh[4 * i + 1] = hv[i].y;
      hh[4 * i + 2] = hv[i].z;
      hh[4 * i + 3] = hv[i].w;
    }
    float ar0 = 0.f, ar1 = 0.f, az0 = 0.f, az1 = 0.f, an0 = 0.f, an1 = 0.f;
#pragma unroll
    for (int i = 0; i < 16; ++i) {
      ar0 = dot2f(whr[2 * i],     hh[2 * i],     ar0);
      ar1 = dot2f(whr[2 * i + 1], hh[2 * i + 1], ar1);
      az0 = dot2f(whz[2 * i],     hh[2 * i],     az0);
      az1 = dot2f(whz[2 * i + 1], hh[2 * i + 1], az1);
      an0 = dot2f(whn[2 * i],     hh[2 * i],     an0);
      an1 = dot2f(whn[2 * i + 1], hh[2 * i + 1], an1);
    }
    float ar = dpp_xor1_add(ar0 + ar1);
    float az = dpp_xor1_add(az0 + az1);
    float an = dpp_xor1_add(an0 + an1);

    half2v x01 = __builtin_bit_cast(half2v, xv.x);
    half2v x23 = __builtin_bit_cast(half2v, xv.y);
    float rr = sigm((float)x01.x + cbr + ar);
    float zz = sigm((float)x01.y + cbz + az);
    float nn = tanhfast((float)x23.x + bin_ + rr * (an + bhn));
    float hnew = nn + zz * (hold - nn);
    if (q == 0) {
      _Float16 hf = (_Float16)hnew;
      hbuf[p ^ 1][c][j] = hf;
      histf[(size_t)(c * CHUNK + s) * HI_LD + j] = hf;
    }
    return hnew;
  };

  for (int ck = 0; ck < NCHUNKS; ++ck) {
    // ---- (a) stage x tile into LDS (f16) ----
    {
      half8 lo, hi;
      lo[0] = (_Float16)px0.x; lo[1] = (_Float16)px0.y; lo[2] = (_Float16)px0.z; lo[3] = (_Float16)px0.w;
      lo[4] = (_Float16)px1.x; lo[5] = (_Float16)px1.y; lo[6] = (_Float16)px1.z; lo[7] = (_Float16)px1.w;
      hi[0] = (_Float16)px2.x; hi[1] = (_Float16)px2.y; hi[2] = (_Float16)px2.z; hi[3] = (_Float16)px2.w;
      hi[4] = (_Float16)px3.x; hi[5] = (_Float16)px3.y; hi[6] = (_Float16)px3.z; hi[7] = (_Float16)px3.w;
      *(half8*)&xAf[prow * XA_LD + cbase] = lo;
      *(half8*)&xAf[prow * XA_LD + cbase + 8] = hi;
    }
    bar_lgkm();

    // ---- (c) MFMA: xp = x @ Wih^T for the tile ----
    {
      floatx4 acc[6][2];
#pragma unroll
      for (int nt = 0; nt < 6; ++nt) {
        acc[nt][0] = (floatx4){0.f, 0.f, 0.f, 0.f};
        acc[nt][1] = (floatx4){0.f, 0.f, 0.f, 0.f};
      }
#pragma unroll
      for (int nt = 0; nt < 6; ++nt) {
        const int g = (wv * 6 + nt) * 16 + mcol;
        const _Float16* wsrc = Wih16 + (size_t)g * DX + mquad * 8;
        half8 bf0 = *(const half8*)(wsrc);
        half8 bf1 = *(const half8*)(wsrc + 32);
        half8 bf2 = *(const half8*)(wsrc + 64);
        half8 bf3 = *(const half8*)(wsrc + 96);
#pragma unroll
        for (int mt = 0; mt < 2; ++mt) {
          const _Float16* ab = &xAf[(mt * 16 + mcol) * XA_LD + mquad * 8];
          acc[nt][mt] = __builtin_amdgcn_mfma_f32_16x16x32_f16(*(const half8*)(ab),      bf0, acc[nt][mt], 0, 0, 0);
          acc[nt][mt] = __builtin_amdgcn_mfma_f32_16x16x32_f16(*(const half8*)(ab + 32), bf1, acc[nt][mt], 0, 0, 0);
          acc[nt][mt] = __builtin_amdgcn_mfma_f32_16x16x32_f16(*(const half8*)(ab + 64), bf2, acc[nt][mt], 0, 0, 0);
          acc[nt][mt] = __builtin_amdgcn_mfma_f32_16x16x32_f16(*(const half8*)(ab + 96), bf3, acc[nt][mt], 0, 0, 0);
        }
      }

      // prefetch next tile's x (waited only at next chunk's staging, not at barriers)
      if (ck + 1 < NCHUNKS) {
        int t = (ck + 1) * CHUNK + ps;
        int t0 = dir ? (T_LEN - 1 - t) : t;
        const float* xp = x + ((size_t)(b0 + pc) * T_LEN + t0) * DX + cbase;
        px0 = *(const float4*)xp;       px1 = *(const float4*)(xp + 4);
        px2 = *(const float4*)(xp + 8); px3 = *(const float4*)(xp + 12);
      }

      // D-stores: row = mt*16 + mquad*4 + i (tile-row), col jj = j*4 + gate
#pragma unroll
      for (int nt = 0; nt < 6; ++nt) {
        const int g  = (wv * 6 + nt) * 16 + mcol;
        const int jj = (g & 127) * 4 + (g >> 7);
#pragma unroll
        for (int mt = 0; mt < 2; ++mt)
#pragma unroll
          for (int i = 0; i < 4; ++i)
            xh2f[(size_t)(mt * 16 + mquad * 4 + i) * XH_W + jj] = (_Float16)acc[nt][mt][i];
      }
    }
    bar_lgkm();

    // ---- (e) scan: CHUNK steps × G interleaved chains ----
#pragma unroll 1
    for (int s = 0; s < CHUNK; ++s) {
      uint4 hA[8], hB[8];
      ldhh(0, hA); uint2 xv0 = ldxv(0, s);
      ldhh(1, hB); uint2 xv1 = ldxv(1, s);
      hold0 = stepc(0, s, hA, xv0, hold0); ldhh(2, hA); uint2 xv2 = ldxv(2, s);
      hold1 = stepc(1, s, hB, xv1, hold1); ldhh(3, hB); uint2 xv3 = ldxv(3, s);
      hold2 = stepc(2, s, hA, xv2, hold2);
      hold3 = stepc(3, s, hB, xv3, hold3);
      p ^= 1;
      bar_lgkm();
    }

    // ---- (f) fused FC over the tile's 32 hidden states ----
    if (wv < 2) {
      const int mt = wv;
      floatx4 facc = (floatx4){0.f, 0.f, 0.f, 0.f};
#pragma unroll
      for (int ks = 0; ks < 4; ++ks) {
        half8 af = *(const half8*)&histf[(size_t)(mt * 16 + mcol) * HI_LD + ks * 32 + mquad * 8];
        facc = __builtin_amdgcn_mfma_f32_16x16x32_f16(af, fcfrag[ks], facc, 0, 0, 0);
      }
      if (mcol < K_CLS) {
#pragma unroll
        for (int i = 0; i < 4; ++i) {
          int r  = mt * 16 + mquad * 4 + i;
          int cc = r >> 3, ss = r & 7;
          int t  = ck * CHUNK + ss;
          int tt = dir ? (T_LEN - 1 - t) : t;
          atomicAdd(out + ((size_t)(b0 + cc) * T_LEN + tt) * K_CLS + mcol, facc[i]);
        }
      }
    }
    // next chunk's (a)-stores hit xAf only; (b)-barrier fences FC's hist reads.
  }
}

extern "C" void kernel_launch(void* const* d_in, const int* in_sizes, int n_in,
                              void* d_out, int out_size, void* d_ws, size_t ws_size,
                              hipStream_t stream) {
  (void)in_sizes; (void)n_in; (void)ws_size; (void)out_size;
  const float* x     = (const float*)d_in[0];
  const float* Wih_f = (const float*)d_in[1];
  const float* Whh_f = (const float*)d_in[2];
  const float* bih_f = (const float*)d_in[3];
  const float* bhh_f = (const float*)d_in[4];
  const float* Wih_b = (const float*)d_in[5];
  const float* Whh_b = (const float*)d_in[6];
  const float* bih_b = (const float*)d_in[7];
  const float* bhh_b = (const float*)d_in[8];
  const float* Wfc   = (const float*)d_in[9];
  const float* bfc   = (const float*)d_in[10];
  float* out = (float*)d_out;

  _Float16* wih16_f = (_Float16*)d_ws;
  _Float16* wih16_b = wih16_f + 3 * H_DIM * DX;

  const int n_out = B_SZ * T_LEN * K_CLS;
  const int n_w   = 3 * H_DIM * DX;
  init_out_kernel<<<(n_out + 255) / 256, 256, 0, stream>>>(out, bfc);
  cvt_wih_kernel<<<(n_w + 255) / 256, 256, 0, stream>>>(Wih_f, Wih_b, wih16_f, wih16_b);
  gru_bidir_kernel<<<(B_SZ * 2) / G, 256, 0, stream>>>(x, Whh_f, bih_f, bhh_f,
                                                       Whh_b, bih_b, bhh_b,
                                                       wih16_f, wih16_b, Wfc, out);
}

// Round 4
// 2408.351 us; speedup vs baseline: 3.3149x; 3.3149x over previous
//
#include <hip/hip_runtime.h>
#include <cstdint>
#include <cstddef>

#define T_LEN   4096
#define B_SZ    32
#define H_DIM   128
#define DX      128
#define K_CLS   10
#define CHUNK   32
#define NCHUNKS (T_LEN / CHUNK)
#define WMAT    (3 * H_DIM * DX)   // 49152 elements per weight matrix
#define XA_LD   136                // halves per x-tile row
#define XP_LD   520                // halves per xp step-row: 128*4 + 8 pad
#define HI_LD   136
#define HA_LD   136                // halves per hA row (A-layout h)

typedef _Float16 half2v  __attribute__((ext_vector_type(2)));
typedef _Float16 half8   __attribute__((ext_vector_type(8)));
typedef float    floatx4 __attribute__((ext_vector_type(4)));

__device__ __forceinline__ float sigm(float x) {
  x = fminf(fmaxf(x, -30.f), 30.f);
  return __builtin_amdgcn_rcpf(1.f + __expf(-x));
}

__device__ __forceinline__ float tanhfast(float x) {
  x = fminf(fmaxf(x, -15.f), 15.f);
  float t = __expf(-2.f * x);
  return (1.f - t) * __builtin_amdgcn_rcpf(1.f + t);
}

// LDS-only barrier: waits ds ops (lgkmcnt) but does NOT drain vmcnt, so the
// in-flight global x-prefetch doesn't stall every scan-step barrier.
__device__ __forceinline__ void bar_lgkm() {
  asm volatile("s_waitcnt lgkmcnt(0)\n\ts_barrier" ::: "memory");
}

__global__ void __launch_bounds__(256) init_out_kernel(float* __restrict__ out,
                                                       const float* __restrict__ bfc) {
  int i = blockIdx.x * 256 + threadIdx.x;
  if (i < B_SZ * T_LEN * K_CLS) out[i] = bfc[i % K_CLS];
}

// Convert the 4 input-weight / recurrent-weight matrices to f16 in ws.
__global__ void __launch_bounds__(256) cvt_w_kernel(const float* __restrict__ a,
                                                    const float* __restrict__ b,
                                                    const float* __restrict__ c,
                                                    const float* __restrict__ d,
                                                    _Float16* __restrict__ o) {
  int i = blockIdx.x * 256 + threadIdx.x;
  if (i < WMAT) {
    o[i]            = (_Float16)a[i];
    o[WMAT + i]     = (_Float16)b[i];
    o[2 * WMAT + i] = (_Float16)c[i];
    o[3 * WMAT + i] = (_Float16)d[i];
  }
}

__global__ void __launch_bounds__(256, 1)
gru_scan_kernel(const float* __restrict__ x,
                const float* __restrict__ bih_f, const float* __restrict__ bhh_f,
                const float* __restrict__ bih_b, const float* __restrict__ bhh_b,
                const _Float16* __restrict__ w16,   // [wih_f|wih_b|whh_f|whh_b]
                const float* __restrict__ Wfc, float* __restrict__ out) {
  const int tid = threadIdx.x;
  const int bid = blockIdx.x;
  const int dir = bid >> 5;
  const int b   = bid & (B_SZ - 1);

  const float* bih = dir ? bih_b : bih_f;
  const float* bhh = dir ? bhh_b : bhh_f;
  const _Float16* Wih16 = w16 + (size_t)dir * WMAT;
  const _Float16* Whh16 = w16 + (size_t)(2 + dir) * WMAT;

  const int lane = tid & 63;
  const int wv   = tid >> 6;     // 0..3
  const int col  = lane & 15;    // MFMA m/n index
  const int quad = lane >> 4;    // MFMA k-group / D-row group

  __shared__ __align__(16) _Float16 xAf[CHUNK * XA_LD];    // x tile (f16)
  __shared__ __align__(16) _Float16 xpL[CHUNK * XP_LD];    // xp: [s][j][gate(3)+pad]
  __shared__ __align__(16) _Float16 histf[CHUNK * HI_LD];  // h history for FC
  __shared__ __align__(16) _Float16 hA[2 * 16 * HA_LD];    // h in A-layout, dbuf; row 0 live, rows 1..15 zero

  // ---- stationary Whh B-fragments: wave wv owns (gate g, j-tile jt) pairs
  // l = jtsel*3 + g, jt = wv + 4*jtsel  → P for j=jt*16+col, gate g is acc[l][0] on quad-0 lanes.
  half8 wb[6][4];
#pragma unroll
  for (int l = 0; l < 6; ++l) {
    const int g  = l % 3;
    const int jt = wv + 4 * (l / 3);
    const int n  = g * 128 + jt * 16 + col;         // row of Whh
    const _Float16* src = Whh16 + (size_t)n * H_DIM + quad * 8;
#pragma unroll
    for (int ks = 0; ks < 4; ++ks) wb[l][ks] = *(const half8*)(src + ks * 32);
  }

  // ---- per-lane gate biases (valid for quad-0 use; harmless elsewhere) ----
  const int j1 = wv * 16 + col;
  const int j2 = j1 + 64;
  const float cbr1 = bih[j1] + bhh[j1];
  const float cbz1 = bih[H_DIM + j1] + bhh[H_DIM + j1];
  const float bin1 = bih[2 * H_DIM + j1];
  const float bhn1 = bhh[2 * H_DIM + j1];
  const float cbr2 = bih[j2] + bhh[j2];
  const float cbz2 = bih[H_DIM + j2] + bhh[H_DIM + j2];
  const float bin2 = bih[2 * H_DIM + j2];
  const float bhn2 = bhh[2 * H_DIM + j2];

  // ---- Wfc fragments (stationary) ----
  half8 fcfrag[4];
#pragma unroll
  for (int ks = 0; ks < 4; ++ks) {
    half8 v;
#pragma unroll
    for (int e = 0; e < 8; ++e) {
      int cc = ks * 32 + quad * 8 + e;
      v[e] = (col < K_CLS) ? (_Float16)Wfc[(size_t)col * (2 * H_DIM) + dir * H_DIM + cc]
                           : (_Float16)0.f;
    }
    fcfrag[ks] = v;
  }

  // ---- zero hA (both buffers; rows 1..15 stay zero forever) ----
  {
    unsigned int* hz = (unsigned int*)hA;
    for (int i = tid; i < (2 * 16 * HA_LD) / 2; i += 256) hz[i] = 0u;
  }

  // ---- x prefetch: thread covers step-row prow, 16 consecutive floats ----
  const int prow  = tid >> 3;          // 0..31
  const int cbase = (tid & 7) * 16;
  float4 px0, px1, px2, px3;
  {
    int t0 = dir ? (T_LEN - 1 - prow) : prow;
    const float* xp = x + ((size_t)b * T_LEN + t0) * DX + cbase;
    px0 = *(const float4*)xp;       px1 = *(const float4*)(xp + 4);
    px2 = *(const float4*)(xp + 8); px3 = *(const float4*)(xp + 12);
  }

  float hold1 = 0.f, hold2 = 0.f;
  __syncthreads();

  for (int ck = 0; ck < NCHUNKS; ++ck) {
    // ---- (a) stage x tile into LDS (f16) ----
    {
      half8 lo, hi;
      lo[0] = (_Float16)px0.x; lo[1] = (_Float16)px0.y; lo[2] = (_Float16)px0.z; lo[3] = (_Float16)px0.w;
      lo[4] = (_Float16)px1.x; lo[5] = (_Float16)px1.y; lo[6] = (_Float16)px1.z; lo[7] = (_Float16)px1.w;
      hi[0] = (_Float16)px2.x; hi[1] = (_Float16)px2.y; hi[2] = (_Float16)px2.z; hi[3] = (_Float16)px2.w;
      hi[4] = (_Float16)px3.x; hi[5] = (_Float16)px3.y; hi[6] = (_Float16)px3.z; hi[7] = (_Float16)px3.w;
      *(half8*)&xAf[prow * XA_LD + cbase] = lo;
      *(half8*)&xAf[prow * XA_LD + cbase + 8] = hi;
    }
    bar_lgkm();

    // ---- (b) xp = x @ Wih^T for the tile (proven R2/R3 structure) ----
    {
#pragma unroll
      for (int nt = 0; nt < 6; ++nt) {
        const int gg = (wv * 6 + nt) * 16 + col;
        const _Float16* wsrc = Wih16 + (size_t)gg * DX + quad * 8;
        half8 bf0 = *(const half8*)(wsrc);
        half8 bf1 = *(const half8*)(wsrc + 32);
        half8 bf2 = *(const half8*)(wsrc + 64);
        half8 bf3 = *(const half8*)(wsrc + 96);
        floatx4 a0 = (floatx4){0.f, 0.f, 0.f, 0.f};
        floatx4 a1 = (floatx4){0.f, 0.f, 0.f, 0.f};
#pragma unroll
        for (int mt = 0; mt < 2; ++mt) {
          const _Float16* ab = &xAf[(mt * 16 + col) * XA_LD + quad * 8];
          floatx4& ac = mt ? a1 : a0;
          ac = __builtin_amdgcn_mfma_f32_16x16x32_f16(*(const half8*)(ab),      bf0, ac, 0, 0, 0);
          ac = __builtin_amdgcn_mfma_f32_16x16x32_f16(*(const half8*)(ab + 32), bf1, ac, 0, 0, 0);
          ac = __builtin_amdgcn_mfma_f32_16x16x32_f16(*(const half8*)(ab + 64), bf2, ac, 0, 0, 0);
          ac = __builtin_amdgcn_mfma_f32_16x16x32_f16(*(const half8*)(ab + 96), bf3, ac, 0, 0, 0);
        }
        // D: row = mt*16 + quad*4 + i (= step s), col gg → xpL[s][j=gg&127][gate=gg>>7]
        const int jj = (gg & 127) * 4 + (gg >> 7);
#pragma unroll
        for (int i = 0; i < 4; ++i) {
          xpL[(quad * 4 + i) * XP_LD + jj]        = (_Float16)a0[i];
          xpL[(16 + quad * 4 + i) * XP_LD + jj]   = (_Float16)a1[i];
        }
      }

      // prefetch next tile's x (waited only at next chunk's staging)
      if (ck + 1 < NCHUNKS) {
        int t = (ck + 1) * CHUNK + prow;
        int t0 = dir ? (T_LEN - 1 - t) : t;
        const float* xp = x + ((size_t)b * T_LEN + t0) * DX + cbase;
        px0 = *(const float4*)xp;       px1 = *(const float4*)(xp + 4);
        px2 = *(const float4*)(xp + 8); px3 = *(const float4*)(xp + 12);
      }
    }
    bar_lgkm();

    // ---- (c) scan: MFMA h-matmul per step, gates in quad-0 lanes ----
    int p = 0;
#pragma unroll 1
    for (int s = 0; s < CHUNK; ++s) {
      // A-fragments of h (row m = col; rows 1..15 are zero)
      const _Float16* hrow = &hA[p * 16 * HA_LD + col * HA_LD + quad * 8];
      half8 a0 = *(const half8*)(hrow);
      half8 a1 = *(const half8*)(hrow + 32);
      half8 a2 = *(const half8*)(hrow + 64);
      half8 a3 = *(const half8*)(hrow + 96);
      // xp gate triples (broadcast across quads)
      uint2 xv1 = *(const uint2*)&xpL[s * XP_LD + j1 * 4];
      uint2 xv2 = *(const uint2*)&xpL[s * XP_LD + j2 * 4];

      floatx4 acc[6];
#pragma unroll
      for (int l = 0; l < 6; ++l) acc[l] = (floatx4){0.f, 0.f, 0.f, 0.f};
#pragma unroll
      for (int l = 0; l < 6; ++l) {
        acc[l] = __builtin_amdgcn_mfma_f32_16x16x32_f16(a0, wb[l][0], acc[l], 0, 0, 0);
        acc[l] = __builtin_amdgcn_mfma_f32_16x16x32_f16(a1, wb[l][1], acc[l], 0, 0, 0);
        acc[l] = __builtin_amdgcn_mfma_f32_16x16x32_f16(a2, wb[l][2], acc[l], 0, 0, 0);
        acc[l] = __builtin_amdgcn_mfma_f32_16x16x32_f16(a3, wb[l][3], acc[l], 0, 0, 0);
      }

      if (quad == 0) {
        // j1: r=acc[0][0], z=acc[1][0], n=acc[2][0]; j2: acc[3..5][0]
        half2v xa1 = __builtin_bit_cast(half2v, xv1.x);
        half2v xb1 = __builtin_bit_cast(half2v, xv1.y);
        half2v xa2 = __builtin_bit_cast(half2v, xv2.x);
        half2v xb2 = __builtin_bit_cast(half2v, xv2.y);
        float rr1 = sigm((float)xa1.x + cbr1 + acc[0][0]);
        float zz1 = sigm((float)xa1.y + cbz1 + acc[1][0]);
        float rr2 = sigm((float)xa2.x + cbr2 + acc[3][0]);
        float zz2 = sigm((float)xa2.y + cbz2 + acc[4][0]);
        float nn1 = tanhfast((float)xb1.x + bin1 + rr1 * (acc[2][0] + bhn1));
        float nn2 = tanhfast((float)xb2.x + bin2 + rr2 * (acc[5][0] + bhn2));
        hold1 = nn1 + zz1 * (hold1 - nn1);
        hold2 = nn2 + zz2 * (hold2 - nn2);
        _Float16 h1 = (_Float16)hold1;
        _Float16 h2 = (_Float16)hold2;
        hA[(p ^ 1) * 16 * HA_LD + j1] = h1;   // row 0 of next buffer
        hA[(p ^ 1) * 16 * HA_LD + j2] = h2;
        histf[s * HI_LD + j1] = h1;
        histf[s * HI_LD + j2] = h2;
      }
      p ^= 1;
      bar_lgkm();
    }

    // ---- (d) fused FC over the chunk's 32 hidden states ----
    if (wv < 2) {
      floatx4 facc = (floatx4){0.f, 0.f, 0.f, 0.f};
#pragma unroll
      for (int ks = 0; ks < 4; ++ks) {
        half8 af = *(const half8*)&histf[(wv * 16 + col) * HI_LD + ks * 32 + quad * 8];
        facc = __builtin_amdgcn_mfma_f32_16x16x32_f16(af, fcfrag[ks], facc, 0, 0, 0);
      }
      if (col < K_CLS) {
#pragma unroll
        for (int i = 0; i < 4; ++i) {
          int s  = wv * 16 + quad * 4 + i;
          int t  = ck * CHUNK + s;
          int tt = dir ? (T_LEN - 1 - t) : t;
          atomicAdd(out + ((size_t)b * T_LEN + tt) * K_CLS + col, facc[i]);
        }
      }
    }
    // hist-overwrite hazard: next chunk's scan writes histf only after the
    // stage+gemm barriers, which FC waves must reach first. xAf restage is
    // fenced from this chunk's gemm reads by the 32 scan barriers.
  }
}

extern "C" void kernel_launch(void* const* d_in, const int* in_sizes, int n_in,
                              void* d_out, int out_size, void* d_ws, size_t ws_size,
                              hipStream_t stream) {
  (void)in_sizes; (void)n_in; (void)ws_size; (void)out_size;
  const float* x     = (const float*)d_in[0];
  const float* Wih_f = (const float*)d_in[1];
  const float* Whh_f = (const float*)d_in[2];
  const float* bih_f = (const float*)d_in[3];
  const float* bhh_f = (const float*)d_in[4];
  const float* Wih_b = (const float*)d_in[5];
  const float* Whh_b = (const float*)d_in[6];
  const float* bih_b = (const float*)d_in[7];
  const float* bhh_b = (const float*)d_in[8];
  const float* Wfc   = (const float*)d_in[9];
  const float* bfc   = (const float*)d_in[10];
  float* out = (float*)d_out;

  _Float16* w16 = (_Float16*)d_ws;   // [wih_f|wih_b|whh_f|whh_b], 4*49152 halves

  const int n_out = B_SZ * T_LEN * K_CLS;
  init_out_kernel<<<(n_out + 255) / 256, 256, 0, stream>>>(out, bfc);
  cvt_w_kernel<<<(WMAT + 255) / 256, 256, 0, stream>>>(Wih_f, Wih_b, Whh_f, Whh_b, w16);
  gru_scan_kernel<<<B_SZ * 2, 256, 0, stream>>>(x, bih_f, bhh_f, bih_b, bhh_b,
                                                w16, Wfc, out);
}